// Round 6
// baseline (372.201 us; speedup 1.0000x reference)
//
#include <hip/hip_runtime.h>
#include <hip/hip_cooperative_groups.h>
#include <math.h>

namespace cg = cooperative_groups;

#define BN_EPS 1e-5f

constexpr int B_ = 4, N_ = 16384, C_ = 64, K_ = 16, O_ = 64;
constexpr int ROWS = B_ * N_;            // 65536
constexpr int ROWS_PER_BLK = 64;
constexpr int NBLK = ROWS / ROWS_PER_BLK; // 1024

// bf16 helpers
__device__ __forceinline__ float b2f(unsigned short u) {
    return __uint_as_float(((unsigned)u) << 16);
}
__device__ __forceinline__ unsigned short f2b(float f) {
    unsigned u = __float_as_uint(f);
    return (unsigned short)((u + 0x7fffu + ((u >> 16) & 1u)) >> 16);
}

// ---------------------------------------------------------------------------
// Pass A: y1[r][o] = x[r]·(W1[o]-W2[o])  (fp32),  y2[r][o] = x[r]·W2[o] (bf16)
// Weight tiles transposed into LDS padded to stride 65 (bank-conflict-free).
// ---------------------------------------------------------------------------
__global__ __launch_bounds__(256) void pass_a(const float* __restrict__ x,
                                              const float* __restrict__ w,
                                              float* __restrict__ y1,
                                              unsigned short* __restrict__ y2) {
    __shared__ float w1m[64 * 65];  // [c][o] = (W1-W2)^T, padded
    __shared__ float w2s[64 * 65];  // [c][o] = W2^T, padded
    __shared__ float xs[64 * 64];   // [r][c]
    const int tid = threadIdx.x;

    for (int i = tid; i < 64 * 64; i += 256) {
        int o = i >> 6, c = i & 63;
        float a = w[o * 128 + c];        // W1[o][c]
        float b = w[o * 128 + 64 + c];   // W2[o][c]
        w1m[c * 65 + o] = a - b;
        w2s[c * 65 + o] = b;
    }
    const long base = (long)blockIdx.x * ROWS_PER_BLK;
    const float* xsrc = x + base * 64;
    for (int i = tid; i < 64 * 64; i += 256) xs[i] = xsrc[i];
    __syncthreads();

    const int o  = tid & 63;
    const int rr = tid >> 6;  // 0..3
    for (int chunk = 0; chunk < 4; ++chunk) {
        const int r0 = chunk * 16 + rr * 4;
        float a1[4] = {0.f, 0.f, 0.f, 0.f};
        float a2[4] = {0.f, 0.f, 0.f, 0.f};
        for (int c4 = 0; c4 < 16; ++c4) {
            float4 xv[4];
#pragma unroll
            for (int j = 0; j < 4; ++j)
                xv[j] = *(const float4*)&xs[(r0 + j) * 64 + c4 * 4];
#pragma unroll
            for (int cc = 0; cc < 4; ++cc) {
                const int c = c4 * 4 + cc;
                const float wv1 = w1m[c * 65 + o];
                const float wv2 = w2s[c * 65 + o];
                const float xj0 = (&xv[0].x)[cc], xj1 = (&xv[1].x)[cc];
                const float xj2 = (&xv[2].x)[cc], xj3 = (&xv[3].x)[cc];
                a1[0] = fmaf(xj0, wv1, a1[0]); a2[0] = fmaf(xj0, wv2, a2[0]);
                a1[1] = fmaf(xj1, wv1, a1[1]); a2[1] = fmaf(xj1, wv2, a2[1]);
                a1[2] = fmaf(xj2, wv1, a1[2]); a2[2] = fmaf(xj2, wv2, a2[2]);
                a1[3] = fmaf(xj3, wv1, a1[3]); a2[3] = fmaf(xj3, wv2, a2[3]);
            }
        }
#pragma unroll
        for (int j = 0; j < 4; ++j) {
            y1[(base + r0 + j) * 64 + o] = a1[j];
            y2[(base + r0 + j) * 64 + o] = f2b(a2[j]);
        }
    }
}

// ---------------------------------------------------------------------------
// Fused B+C+D (cooperative, 1024 blocks x 256, 4 blocks/CU co-resident):
//  Phase 2: gather h = y1 + b2f(y2[idx]); signed-space extremum e = sgn*h
//           kept in LDS (no exth global round-trip); per-channel partials.
//  Phase 3: blocks 0..63 reduce partials (double) -> ss[scale|shift].
//  Phase 4: out = relu(|scale| * e + shift) straight from LDS.
// LDS = 26.6 KB/block; __launch_bounds__(256,4) caps VGPR<=128 so 4
// blocks/CU co-residency for the cooperative launch is guaranteed.
// ---------------------------------------------------------------------------
__global__ __launch_bounds__(256, 4) void pass_bcd(
        const float* __restrict__ y1,
        const unsigned short* __restrict__ y2,
        const int* __restrict__ idx,
        const float* __restrict__ gamma,
        const float* __restrict__ beta,
        float* __restrict__ partial,
        float* __restrict__ ss,
        float* __restrict__ out) {
    __shared__ int sidx[ROWS_PER_BLK * K_];  // 4 KB
    __shared__ float eL[64 * 64];            // 16 KB, signed-space extremum
    __shared__ float reds[4][64];            // 1 KB
    __shared__ float redq[4][64];            // 1 KB
    __shared__ double rs[256];               // 2 KB
    __shared__ double rq[256];               // 2 KB

    const int tid = threadIdx.x;
    const int blk = blockIdx.x;
    const int xcd = blk & 7;
    const int bt = xcd >> 1;                         // batch for this XCD pair
    const int slot = ((blk >> 3) << 1) | (xcd & 1);  // 0..255 within batch
    const long base = (long)bt * N_ + (long)slot * ROWS_PER_BLK;

    ((int4*)sidx)[tid] = ((const int4*)(idx + base * K_))[tid];

    const int lane = tid & 63;
    const int wv   = tid >> 6;   // wave 0..3
    const int ksub = lane >> 4;  // 0..3
    const int c4   = lane & 15;  // channel quad: channels 4*c4..4*c4+3
    const unsigned short* y2b = y2 + (long)bt * N_ * 64;

    const float4 gm = ((const float4*)gamma)[c4];
    const float4 sgn = make_float4(gm.x >= 0.f ? 1.f : -1.f,
                                   gm.y >= 0.f ? 1.f : -1.f,
                                   gm.z >= 0.f ? 1.f : -1.f,
                                   gm.w >= 0.f ? 1.f : -1.f);
    __syncthreads();

    float4 psum = make_float4(0.f, 0.f, 0.f, 0.f);
    float4 psq  = make_float4(0.f, 0.f, 0.f, 0.f);

    for (int rl = wv; rl < ROWS_PER_BLK; rl += 4) {  // 16 rows per wave
        const long row = base + rl;
        const float4 y1v = ((const float4*)(y1 + row * 64))[c4];
        float4 e = make_float4(-3.402823466e+38f, -3.402823466e+38f,
                               -3.402823466e+38f, -3.402823466e+38f);
#pragma unroll
        for (int kk = 0; kk < 4; ++kk) {
            const int m = sidx[rl * K_ + kk * 4 + ksub];
            const ushort4 v = *(const ushort4*)(y2b + (long)m * 64 + c4 * 4);
            const float hx = y1v.x + b2f(v.x), hy = y1v.y + b2f(v.y);
            const float hz = y1v.z + b2f(v.z), hw = y1v.w + b2f(v.w);
            e.x = fmaxf(e.x, sgn.x * hx); e.y = fmaxf(e.y, sgn.y * hy);
            e.z = fmaxf(e.z, sgn.z * hz); e.w = fmaxf(e.w, sgn.w * hw);
            psum.x += hx; psum.y += hy; psum.z += hz; psum.w += hw;
            psq.x = fmaf(hx, hx, psq.x); psq.y = fmaf(hy, hy, psq.y);
            psq.z = fmaf(hz, hz, psq.z); psq.w = fmaf(hw, hw, psq.w);
        }
#pragma unroll
        for (int d = 16; d <= 32; d <<= 1) {
            e.x = fmaxf(e.x, __shfl_xor(e.x, d));
            e.y = fmaxf(e.y, __shfl_xor(e.y, d));
            e.z = fmaxf(e.z, __shfl_xor(e.z, d));
            e.w = fmaxf(e.w, __shfl_xor(e.w, d));
        }
        if (ksub == 0)
            *(float4*)&eL[rl * 64 + c4 * 4] = e;  // signed space
    }
#pragma unroll
    for (int d = 16; d <= 32; d <<= 1) {
        psum.x += __shfl_xor(psum.x, d); psum.y += __shfl_xor(psum.y, d);
        psum.z += __shfl_xor(psum.z, d); psum.w += __shfl_xor(psum.w, d);
        psq.x  += __shfl_xor(psq.x, d);  psq.y  += __shfl_xor(psq.y, d);
        psq.z  += __shfl_xor(psq.z, d);  psq.w  += __shfl_xor(psq.w, d);
    }
    if (ksub == 0) {
        *(float4*)&reds[wv][c4 * 4] = psum;
        *(float4*)&redq[wv][c4 * 4] = psq;
    }
    __syncthreads();
    if (tid < 64) {
        const float s = reds[0][tid] + reds[1][tid] + reds[2][tid] + reds[3][tid];
        const float q = redq[0][tid] + redq[1][tid] + redq[2][tid] + redq[3][tid];
        partial[blk * 128 + tid] = s;
        partial[blk * 128 + 64 + tid] = q;
    }
    __threadfence();

    cg::this_grid().sync();

    // ---- Phase 3: blocks 0..63 compute scale/shift for channel blk ----
    if (blk < 64) {
        const int o = blk;
        double as = 0.0, aq = 0.0;
        for (int i = tid; i < NBLK; i += 256) {
            as += (double)partial[i * 128 + o];
            aq += (double)partial[i * 128 + 64 + o];
        }
        rs[tid] = as;
        rq[tid] = aq;
        __syncthreads();
        for (int s = 128; s > 0; s >>= 1) {
            if (tid < s) { rs[tid] += rs[tid + s]; rq[tid] += rq[tid + s]; }
            __syncthreads();
        }
        if (tid == 0) {
            const double cnt = (double)B_ * N_ * K_;  // 1,048,576
            double mean = rs[0] / cnt;
            double var = rq[0] / cnt - mean * mean;
            float scale = gamma[o] * (float)(1.0 / sqrt(var + (double)BN_EPS));
            float shift = beta[o] - (float)mean * scale;
            ss[o] = scale;
            ss[64 + o] = shift;
        }
        __threadfence();
    }

    cg::this_grid().sync();

    // ---- Phase 4: out = relu(|scale| * e + shift), e from LDS ----
    if (tid < 64) {
        reds[0][tid] = fabsf(ss[tid]);  // |scale| (sgn folded into e)
        reds[1][tid] = ss[64 + tid];    // shift
    }
    __syncthreads();
    for (int i = tid; i < 1024; i += 256) {   // 64 rows x 16 float4s
        const int row = i >> 4;
        const int c0 = (i & 15) * 4;
        const float4 e4 = *(const float4*)&eL[row * 64 + c0];
        float4 r;
        r.x = fmaxf(fmaf(reds[0][c0],     e4.x, reds[1][c0]),     0.f);
        r.y = fmaxf(fmaf(reds[0][c0 + 1], e4.y, reds[1][c0 + 1]), 0.f);
        r.z = fmaxf(fmaf(reds[0][c0 + 2], e4.z, reds[1][c0 + 2]), 0.f);
        r.w = fmaxf(fmaf(reds[0][c0 + 3], e4.w, reds[1][c0 + 3]), 0.f);
        *(float4*)&out[(base + row) * 64 + c0] = r;
    }
}

extern "C" void kernel_launch(void* const* d_in, const int* in_sizes, int n_in,
                              void* d_out, int out_size, void* d_ws, size_t ws_size,
                              hipStream_t stream) {
    const float* x     = (const float*)d_in[0];
    const int*   idx   = (const int*)d_in[1];
    const float* w     = (const float*)d_in[2];
    const float* gamma = (const float*)d_in[3];
    const float* beta  = (const float*)d_in[4];
    float* out = (float*)d_out;

    char* ws = (char*)d_ws;
    float*          y1      = (float*)ws;                          // 16.8 MB
    unsigned short* y2      = (unsigned short*)(ws + 16777216);    //  8.4 MB
    float*          partial = (float*)(ws + 25165824);             //  0.5 MB
    float*          ss      = (float*)(ws + 25690112);             //  512 B

    pass_a<<<NBLK, 256, 0, stream>>>(x, w, y1, y2);

    void* args[] = {(void*)&y1, (void*)&y2, (void*)&idx, (void*)&gamma,
                    (void*)&beta, (void*)&partial, (void*)&ss, (void*)&out};
    hipLaunchCooperativeKernel((const void*)pass_bcd, dim3(NBLK), dim3(256),
                               args, 0, stream);
}

// Round 7
// 128.689 us; speedup vs baseline: 2.8923x; 2.8923x over previous
//
#include <hip/hip_runtime.h>
#include <math.h>

#define BN_EPS 1e-5f

constexpr int B_ = 4, N_ = 16384, C_ = 64, K_ = 16, O_ = 64;
constexpr int ROWS = B_ * N_;            // 65536
constexpr int ROWS_PER_BLK_A = 64;
constexpr int NBLK_A = ROWS / ROWS_PER_BLK_A;  // 1024
constexpr int RPB_B = 32;                      // rows per block, pass_b
constexpr int NBLK_B = ROWS / RPB_B;           // 2048 -> 8 blocks/CU

// bf16 helpers
__device__ __forceinline__ float b2f(unsigned short u) {
    return __uint_as_float(((unsigned)u) << 16);
}
__device__ __forceinline__ unsigned short f2b(float f) {
    unsigned u = __float_as_uint(f);
    return (unsigned short)((u + 0x7fffu + ((u >> 16) & 1u)) >> 16);
}

// ---------------------------------------------------------------------------
// Pass A: y1[r][o] = x[r]·(W1[o]-W2[o])  (fp32),  y2[r][o] = x[r]·W2[o] (bf16)
// Weight tiles transposed into LDS padded to stride 65 (bank-conflict-free).
// ---------------------------------------------------------------------------
__global__ __launch_bounds__(256) void pass_a(const float* __restrict__ x,
                                              const float* __restrict__ w,
                                              float* __restrict__ y1,
                                              unsigned short* __restrict__ y2) {
    __shared__ float w1m[64 * 65];  // [c][o] = (W1-W2)^T, padded
    __shared__ float w2s[64 * 65];  // [c][o] = W2^T, padded
    __shared__ float xs[64 * 64];   // [r][c]
    const int tid = threadIdx.x;

    for (int i = tid; i < 64 * 64; i += 256) {
        int o = i >> 6, c = i & 63;
        float a = w[o * 128 + c];        // W1[o][c]
        float b = w[o * 128 + 64 + c];   // W2[o][c]
        w1m[c * 65 + o] = a - b;
        w2s[c * 65 + o] = b;
    }
    const long base = (long)blockIdx.x * ROWS_PER_BLK_A;
    const float* xsrc = x + base * 64;
    for (int i = tid; i < 64 * 64; i += 256) xs[i] = xsrc[i];
    __syncthreads();

    const int o  = tid & 63;
    const int rr = tid >> 6;  // 0..3
    for (int chunk = 0; chunk < 4; ++chunk) {
        const int r0 = chunk * 16 + rr * 4;
        float a1[4] = {0.f, 0.f, 0.f, 0.f};
        float a2[4] = {0.f, 0.f, 0.f, 0.f};
        for (int c4 = 0; c4 < 16; ++c4) {
            float4 xv[4];
#pragma unroll
            for (int j = 0; j < 4; ++j)
                xv[j] = *(const float4*)&xs[(r0 + j) * 64 + c4 * 4];
#pragma unroll
            for (int cc = 0; cc < 4; ++cc) {
                const int c = c4 * 4 + cc;
                const float wv1 = w1m[c * 65 + o];
                const float wv2 = w2s[c * 65 + o];
                const float xj0 = (&xv[0].x)[cc], xj1 = (&xv[1].x)[cc];
                const float xj2 = (&xv[2].x)[cc], xj3 = (&xv[3].x)[cc];
                a1[0] = fmaf(xj0, wv1, a1[0]); a2[0] = fmaf(xj0, wv2, a2[0]);
                a1[1] = fmaf(xj1, wv1, a1[1]); a2[1] = fmaf(xj1, wv2, a2[1]);
                a1[2] = fmaf(xj2, wv1, a1[2]); a2[2] = fmaf(xj2, wv2, a2[2]);
                a1[3] = fmaf(xj3, wv1, a1[3]); a2[3] = fmaf(xj3, wv2, a2[3]);
            }
        }
#pragma unroll
        for (int j = 0; j < 4; ++j) {
            y1[(base + r0 + j) * 64 + o] = a1[j];
            y2[(base + r0 + j) * 64 + o] = f2b(a2[j]);
        }
    }
}

// ---------------------------------------------------------------------------
// Pass B (latency-hiding rework): 2048 blocks x 32 rows -> 8 blocks/CU =
// 32 waves/CU (hardware max). Each wave owns 8 rows, processed in PAIRS with
// all 8 gathers + 2 y1 loads issued before any consumption (~10 vmem in
// flight per wave). Signed extremum (gamma sign folded) -> exth (bf16);
// per-channel sum/sumsq partials. XCD-affine remap keeps each XCD's gathers
// inside one batch's 2.1 MB y2 slice (~its private L2).
// ---------------------------------------------------------------------------
__global__ __launch_bounds__(256) void pass_b(const float* __restrict__ y1,
                                              const unsigned short* __restrict__ y2,
                                              const int* __restrict__ idx,
                                              const float* __restrict__ gamma,
                                              unsigned short* __restrict__ exth,
                                              float* __restrict__ partial) {
    __shared__ int sidx[RPB_B * K_];  // 512 ints
    __shared__ float reds[4][64];
    __shared__ float redq[4][64];
    const int tid = threadIdx.x;
    const int blk = blockIdx.x;
    const int xcd = blk & 7;
    const int bt = xcd >> 1;                         // batch for this XCD pair
    const int slot = ((blk >> 3) << 1) | (xcd & 1);  // 0..511 within batch
    const long base = (long)bt * N_ + (long)slot * RPB_B;

    ((int2*)sidx)[tid] = ((const int2*)(idx + base * K_))[tid];  // 512 ints

    const int lane = tid & 63;
    const int wv   = tid >> 6;   // wave 0..3
    const int ksub = lane >> 4;  // 0..3
    const int c4   = lane & 15;  // channel quad: channels 4*c4..4*c4+3
    const unsigned short* y2b = y2 + (long)bt * N_ * 64;

    const float4 gm = ((const float4*)gamma)[c4];
    const float4 sgn = make_float4(gm.x >= 0.f ? 1.f : -1.f,
                                   gm.y >= 0.f ? 1.f : -1.f,
                                   gm.z >= 0.f ? 1.f : -1.f,
                                   gm.w >= 0.f ? 1.f : -1.f);
    __syncthreads();

    float4 psum = make_float4(0.f, 0.f, 0.f, 0.f);
    float4 psq  = make_float4(0.f, 0.f, 0.f, 0.f);

    // wave wv owns rows [wv*8, wv*8+8); two rows per iteration
    for (int j = 0; j < 8; j += 2) {
        const int rlA = wv * 8 + j;
        const int rlB = rlA + 1;
        const long rowA = base + rlA, rowB = base + rlB;

        // ---- issue all loads first (10 independent vmem ops) ----
        const float4 y1A = ((const float4*)(y1 + rowA * 64))[c4];
        const float4 y1B = ((const float4*)(y1 + rowB * 64))[c4];
        ushort4 vA[4], vB[4];
#pragma unroll
        for (int kk = 0; kk < 4; ++kk) {
            const int mA = sidx[rlA * K_ + kk * 4 + ksub];
            const int mB = sidx[rlB * K_ + kk * 4 + ksub];
            vA[kk] = *(const ushort4*)(y2b + (long)mA * 64 + c4 * 4);
            vB[kk] = *(const ushort4*)(y2b + (long)mB * 64 + c4 * 4);
        }

        // ---- consume ----
        float4 eA = make_float4(-3.402823466e+38f, -3.402823466e+38f,
                                -3.402823466e+38f, -3.402823466e+38f);
        float4 eB = eA;
#pragma unroll
        for (int kk = 0; kk < 4; ++kk) {
            {
                const float hx = y1A.x + b2f(vA[kk].x), hy = y1A.y + b2f(vA[kk].y);
                const float hz = y1A.z + b2f(vA[kk].z), hw = y1A.w + b2f(vA[kk].w);
                eA.x = fmaxf(eA.x, sgn.x * hx); eA.y = fmaxf(eA.y, sgn.y * hy);
                eA.z = fmaxf(eA.z, sgn.z * hz); eA.w = fmaxf(eA.w, sgn.w * hw);
                psum.x += hx; psum.y += hy; psum.z += hz; psum.w += hw;
                psq.x = fmaf(hx, hx, psq.x); psq.y = fmaf(hy, hy, psq.y);
                psq.z = fmaf(hz, hz, psq.z); psq.w = fmaf(hw, hw, psq.w);
            }
            {
                const float hx = y1B.x + b2f(vB[kk].x), hy = y1B.y + b2f(vB[kk].y);
                const float hz = y1B.z + b2f(vB[kk].z), hw = y1B.w + b2f(vB[kk].w);
                eB.x = fmaxf(eB.x, sgn.x * hx); eB.y = fmaxf(eB.y, sgn.y * hy);
                eB.z = fmaxf(eB.z, sgn.z * hz); eB.w = fmaxf(eB.w, sgn.w * hw);
                psum.x += hx; psum.y += hy; psum.z += hz; psum.w += hw;
                psq.x = fmaf(hx, hx, psq.x); psq.y = fmaf(hy, hy, psq.y);
                psq.z = fmaf(hz, hz, psq.z); psq.w = fmaf(hw, hw, psq.w);
            }
        }
        // reduce over the 4 ksub groups (lanes 16 apart)
#pragma unroll
        for (int d = 16; d <= 32; d <<= 1) {
            eA.x = fmaxf(eA.x, __shfl_xor(eA.x, d));
            eA.y = fmaxf(eA.y, __shfl_xor(eA.y, d));
            eA.z = fmaxf(eA.z, __shfl_xor(eA.z, d));
            eA.w = fmaxf(eA.w, __shfl_xor(eA.w, d));
            eB.x = fmaxf(eB.x, __shfl_xor(eB.x, d));
            eB.y = fmaxf(eB.y, __shfl_xor(eB.y, d));
            eB.z = fmaxf(eB.z, __shfl_xor(eB.z, d));
            eB.w = fmaxf(eB.w, __shfl_xor(eB.w, d));
        }
        if (ksub == 0) {
            ushort4 rA, rB;
            rA.x = f2b(sgn.x * eA.x); rA.y = f2b(sgn.y * eA.y);
            rA.z = f2b(sgn.z * eA.z); rA.w = f2b(sgn.w * eA.w);
            rB.x = f2b(sgn.x * eB.x); rB.y = f2b(sgn.y * eB.y);
            rB.z = f2b(sgn.z * eB.z); rB.w = f2b(sgn.w * eB.w);
            *(ushort4*)(exth + rowA * 64 + c4 * 4) = rA;
            *(ushort4*)(exth + rowB * 64 + c4 * 4) = rB;
        }
    }
    // reduce per-lane partial sums over ksub groups
#pragma unroll
    for (int d = 16; d <= 32; d <<= 1) {
        psum.x += __shfl_xor(psum.x, d); psum.y += __shfl_xor(psum.y, d);
        psum.z += __shfl_xor(psum.z, d); psum.w += __shfl_xor(psum.w, d);
        psq.x  += __shfl_xor(psq.x, d);  psq.y  += __shfl_xor(psq.y, d);
        psq.z  += __shfl_xor(psq.z, d);  psq.w  += __shfl_xor(psq.w, d);
    }
    if (ksub == 0) {
        *(float4*)&reds[wv][c4 * 4] = psum;
        *(float4*)&redq[wv][c4 * 4] = psq;
    }
    __syncthreads();
    if (tid < 64) {
        const float s = reds[0][tid] + reds[1][tid] + reds[2][tid] + reds[3][tid];
        const float q = redq[0][tid] + redq[1][tid] + redq[2][tid] + redq[3][tid];
        partial[blk * 128 + tid] = s;
        partial[blk * 128 + 64 + tid] = q;
    }
}

// ---------------------------------------------------------------------------
// Pass C: 64 blocks, one per channel; double-precision reduction of the
// 2048 block partials; emits scale/shift.
// ---------------------------------------------------------------------------
__global__ __launch_bounds__(256) void pass_c(const float* __restrict__ partial,
                                              const float* __restrict__ gamma,
                                              const float* __restrict__ beta,
                                              float* __restrict__ ss) {
    __shared__ double rs[256];
    __shared__ double rq[256];
    const int o = blockIdx.x;
    const int tid = threadIdx.x;
    double as = 0.0, aq = 0.0;
    for (int i = tid; i < NBLK_B; i += 256) {
        as += (double)partial[i * 128 + o];
        aq += (double)partial[i * 128 + 64 + o];
    }
    rs[tid] = as;
    rq[tid] = aq;
    __syncthreads();
    for (int s = 128; s > 0; s >>= 1) {
        if (tid < s) { rs[tid] += rs[tid + s]; rq[tid] += rq[tid + s]; }
        __syncthreads();
    }
    if (tid == 0) {
        const double cnt = (double)B_ * N_ * K_;  // 1,048,576
        double mean = rs[0] / cnt;
        double var = rq[0] / cnt - mean * mean;
        float scale = gamma[o] * (float)(1.0 / sqrt(var + (double)BN_EPS));
        float shift = beta[o] - (float)mean * scale;
        ss[o] = scale;
        ss[64 + o] = shift;
    }
}

// ---------------------------------------------------------------------------
// Pass D: out = relu(scale * exth + shift); exth is bf16 (8 elts per thread).
// ---------------------------------------------------------------------------
__global__ __launch_bounds__(256) void pass_d(const unsigned short* __restrict__ exth,
                                              const float* __restrict__ ss,
                                              float* __restrict__ out) {
    __shared__ float sscale[64], sshift[64];
    const int tid = threadIdx.x;
    if (tid < 64) { sscale[tid] = ss[tid]; sshift[tid] = ss[64 + tid]; }
    __syncthreads();
    const uint4* ep = (const uint4*)exth;   // 8 bf16 per uint4
    const long total8 = (long)ROWS * 64 / 8;  // 524,288
    for (long i = (long)blockIdx.x * 256 + tid; i < total8;
         i += (long)gridDim.x * 256) {
        const int c0 = ((int)i * 8) & 63;
        const uint4 u = ep[i];
        const unsigned uu[4] = {u.x, u.y, u.z, u.w};
        float r[8];
#pragma unroll
        for (int j = 0; j < 4; ++j) {
            const float e0 = __uint_as_float(uu[j] << 16);
            const float e1 = __uint_as_float(uu[j] & 0xffff0000u);
            r[2 * j]     = fmaxf(fmaf(sscale[c0 + 2 * j],     e0, sshift[c0 + 2 * j]),     0.f);
            r[2 * j + 1] = fmaxf(fmaf(sscale[c0 + 2 * j + 1], e1, sshift[c0 + 2 * j + 1]), 0.f);
        }
        ((float4*)out)[2 * i]     = make_float4(r[0], r[1], r[2], r[3]);
        ((float4*)out)[2 * i + 1] = make_float4(r[4], r[5], r[6], r[7]);
    }
}

extern "C" void kernel_launch(void* const* d_in, const int* in_sizes, int n_in,
                              void* d_out, int out_size, void* d_ws, size_t ws_size,
                              hipStream_t stream) {
    const float* x     = (const float*)d_in[0];
    const int*   idx   = (const int*)d_in[1];
    const float* w     = (const float*)d_in[2];
    const float* gamma = (const float*)d_in[3];
    const float* beta  = (const float*)d_in[4];
    float* out = (float*)d_out;

    char* ws = (char*)d_ws;
    float*          y1      = (float*)ws;                          // 16.8 MB
    unsigned short* y2      = (unsigned short*)(ws + 16777216);    //  8.4 MB
    unsigned short* exth    = (unsigned short*)(ws + 25165824);    //  8.4 MB
    float*          partial = (float*)(ws + 33554432);             //  1.0 MB
    float*          ss      = (float*)(ws + 34603008);             //  512 B

    pass_a<<<NBLK_A, 256, 0, stream>>>(x, w, y1, y2);
    pass_b<<<NBLK_B, 256, 0, stream>>>(y1, y2, idx, gamma, exth, partial);
    pass_c<<<64, 256, 0, stream>>>(partial, gamma, beta, ss);
    pass_d<<<2048, 256, 0, stream>>>(exth, ss, out);
}